// Round 13
// baseline (265.640 us; speedup 1.0000x reference)
//
#include <hip/hip_runtime.h>
#include <math.h>

#define N   8192
#define D   512
#define C   16
#define HM  256
#define HG  64
#define KMAX 128   // max neighbors per row (mean ~65, 12-sigma safe)
#define INF 0x7FFFFFFF
#define HP  2048   // H-partial blocks (= row groups; full TLP, no grid-stride)

typedef __attribute__((ext_vector_type(8))) short bf16x8;
typedef __attribute__((ext_vector_type(4))) float f32x4;

__device__ __forceinline__ unsigned short f2b(float x) {
  union { float f; unsigned int u; } v; v.f = x;
  unsigned int r = v.u + 0x7FFFu + ((v.u >> 16) & 1u);  // RNE
  return (unsigned short)(r >> 16);
}
__device__ __forceinline__ float b2f(unsigned short b) {
  union { unsigned int u; float f; } v; v.u = ((unsigned int)b) << 16;
  return v.f;
}

// ---------------- K0: prep: feature->bf16, Wcat->bf16 T, Wm2->bf16 T, rowcnt=0 -----------------
__global__ __launch_bounds__(256) void prep_kernel(const float* __restrict__ feat,
    const float* __restrict__ Wm1, const float* __restrict__ W1,
    const float* __restrict__ Wm2, unsigned short* __restrict__ Abf,
    unsigned short* __restrict__ Wt, unsigned short* __restrict__ Wm2tb,
    int* __restrict__ rowcnt) {
  const int tid = blockIdx.x * 256 + threadIdx.x;  // 524288 threads
  const float4 a = *(const float4*)&feat[(size_t)tid * 8];
  const float4 b = *(const float4*)&feat[(size_t)tid * 8 + 4];
  ushort4 lo, hi;
  lo.x = f2b(a.x); lo.y = f2b(a.y); lo.z = f2b(a.z); lo.w = f2b(a.w);
  hi.x = f2b(b.x); hi.y = f2b(b.y); hi.z = f2b(b.z); hi.w = f2b(b.w);
  *(ushort4*)&Abf[(size_t)tid * 8] = lo;
  *(ushort4*)&Abf[(size_t)tid * 8 + 4] = hi;
  if (tid < 320 * 512) {  // Wt[n][k]
    const int n = tid >> 9, k = tid & 511;
    const float v = (n < 256) ? Wm1[k * 256 + n] : W1[k * 64 + (n - 256)];
    Wt[tid] = f2b(v);
  }
  if (tid < 16 * 256) {   // Wm2tb[c][k] = Wm2[k][c]
    const int cc = tid >> 8, k = tid & 255;
    Wm2tb[tid] = f2b(Wm2[k * 16 + cc]);
  }
  if (tid < N) rowcnt[tid] = 0;
}

// ---------------- K1: adj upper-triangle scan, 4 balanced rows/block (R9-proven config) --------
__global__ __launch_bounds__(256) void adj_tri(const float* __restrict__ adj,
    int* __restrict__ rowcnt, int* __restrict__ colidx) {
  const int t = threadIdx.x, b = blockIdx.x;  // b in [0,2048)
  int rows[4];
  rows[0] = 2 * b; rows[1] = 2 * b + 1;
  rows[2] = N - 2 - 2 * b; rows[3] = N - 1 - 2 * b;
  const float4* base[4];
  int c0[4], nch[4];
  int maxn = 0;
  #pragma unroll
  for (int r = 0; r < 4; ++r) {
    c0[r] = rows[r] & ~3;
    nch[r] = (N - c0[r]) >> 2;
    base[r] = (const float4*)(adj + (size_t)rows[r] * N + c0[r]);
    maxn = max(maxn, nch[r]);
  }
  for (int p = t; p < maxn; p += 256) {
    float4 v[4];
    bool act[4];
    #pragma unroll
    for (int r = 0; r < 4; ++r) {
      act[r] = p < nch[r];
      if (act[r]) v[r] = base[r][p];    // 4 independent loads in flight
    }
    #pragma unroll
    for (int r = 0; r < 4; ++r) {
      if (!act[r]) continue;
      const float4 vv = v[r];
      if (vv.x + vv.y + vv.z + vv.w > 0.f) {   // adj is 0/1: skip all-zero chunks
        const int row = rows[r];
        const int j = c0[r] + p * 4;
        const float e[4] = {vv.x, vv.y, vv.z, vv.w};
        #pragma unroll
        for (int q = 0; q < 4; ++q) {
          const int jj = j + q;
          if (e[q] > 0.f && jj >= row) {
            int pos = atomicAdd(&rowcnt[row], 1);
            if (pos < KMAX) colidx[row * KMAX + pos] = jj;
            if (jj > row) {
              pos = atomicAdd(&rowcnt[jj], 1);
              if (pos < KMAX) colidx[(size_t)jj * KMAX + pos] = row;
            }
          }
        }
      }
    }
  }
}

// ---------------- K2: GEMM (BM=32, 256 blocks) + MLP layer2 + softmax; X1 stored bf16 ----------
__global__ __launch_bounds__(256) void gemm_mlp(
    const bf16x8* __restrict__ Abf, const bf16x8* __restrict__ Wt,
    const float* __restrict__ bm1, const bf16x8* __restrict__ Wm2tb,
    const float* __restrict__ bm2, const float* __restrict__ labels1h,
    const int* __restrict__ mask, float* __restrict__ Bmat,
    float* __restrict__ softy, unsigned short* __restrict__ X1b) {
  __shared__ unsigned short c1[32][264];   // bf16 C1 tile (row stride 528B)
  const int l = threadIdx.x & 63, w = threadIdx.x >> 6;
  const int m0 = blockIdx.x * 32;
  const int kb = l >> 4, cl = l & 15;
  const int rw = (w >> 1) * 16;          // row half: 0 or 16
  const int nt0 = (w & 1) * 10;          // tile half: 0..9 or 10..19
  const int row = m0 + rw + cl;
  const bf16x8* arow = Abf + (size_t)row * 64 + kb;
  f32x4 acc[10] = {};
  for (int kk = 0; kk < 16; ++kk) {
    const bf16x8 af = arow[kk * 4];
    #pragma unroll
    for (int i = 0; i < 10; ++i) {
      const bf16x8 bfr = Wt[(size_t)((nt0 + i) * 16 + cl) * 64 + kk * 4 + kb];
      acc[i] = __builtin_amdgcn_mfma_f32_16x16x32_bf16(af, bfr, acc[i], 0, 0, 0);
    }
  }
  // epilogue: C/D layout col=l&15, row=(l>>4)*4+r
  const int rl0 = rw + kb * 4;
  #pragma unroll
  for (int i = 0; i < 10; ++i) {
    const int nt = nt0 + i;
    const int col = nt * 16 + cl;
    if (nt < 16) {
      const float bv = bm1[col];
      #pragma unroll
      for (int r = 0; r < 4; ++r)
        c1[rl0 + r][col] = f2b(fmaxf(acc[i][r] + bv, 0.f));
    } else {
      const int xc = col - 256;
      #pragma unroll
      for (int r = 0; r < 4; ++r)
        X1b[(size_t)(m0 + rl0 + r) * HG + xc] = f2b(acc[i][r]);
    }
  }
  __syncthreads();
  // layer 2 (waves 0,2): B = softmax(C1 @ Wm2 + bm2) for rows m0+rw..+15
  if ((w & 1) == 0) {
    f32x4 acc2 = {0.f, 0.f, 0.f, 0.f};
    #pragma unroll
    for (int kk = 0; kk < 8; ++kk) {
      const bf16x8 a2 = *(const bf16x8*)&c1[rw + cl][kk * 32 + kb * 8];
      const bf16x8 b2v = Wm2tb[(size_t)cl * 32 + kk * 4 + kb];
      acc2 = __builtin_amdgcn_mfma_f32_16x16x32_bf16(a2, b2v, acc2, 0, 0, 0);
    }
    const float bm2v = bm2[cl];
    #pragma unroll
    for (int r = 0; r < 4; ++r) {
      float v = acc2[r] + bm2v;
      float m = v;
      #pragma unroll
      for (int s = 1; s < 16; s <<= 1) m = fmaxf(m, __shfl_xor(m, s));
      const float e = __expf(v - m);
      float ssum = e;
      #pragma unroll
      for (int s = 1; s < 16; s <<= 1) ssum += __shfl_xor(ssum, s);
      const float bb = e / ssum;
      const int grow = m0 + rw + kb * 4 + r;
      Bmat[grow * C + cl] = bb;
      softy[grow * C + cl] = mask[grow] ? labels1h[grow * C + cl] : bb;
    }
  }
}

// ---------------- K3: sort + nbrsum(LDS) + per-block H partial (2048 blocks, 1 group each) -----
__global__ __launch_bounds__(256) void sort_nbr_h(int* __restrict__ rowcnt,
    int* __restrict__ colidx, const float* __restrict__ softy,
    float* __restrict__ Hpart) {
  __shared__ int cs[4][128];
  __shared__ float nb[4][16], sy[4][16];
  const int t = threadIdx.x, lane = t & 63, w = t >> 6;
  const int c = t >> 4, cp = t & 15;
  const int g = blockIdx.x;
  const int row = g * 4 + w;
  const int cnt = min(rowcnt[row], KMAX);
  if (lane == 0) rowcnt[row] = cnt;
  int e0 = (lane < cnt) ? colidx[row * KMAX + lane] : INF;
  int e1 = (lane + 64 < cnt) ? colidx[row * KMAX + lane + 64] : INF;
  #pragma unroll
  for (int k = 2; k <= 128; k <<= 1) {
    if (k == 128) { const int mn = min(e0, e1), mx = max(e0, e1); e0 = mn; e1 = mx; }
    #pragma unroll
    for (int j = (k == 128) ? 32 : (k >> 1); j > 0; j >>= 1) {
      const bool up = (lane & k) == 0;
      const bool upHi = ((lane + 64) & k) == 0;
      const bool lower = (lane & j) == 0;
      const int o0 = __shfl_xor(e0, j);
      const int o1 = __shfl_xor(e1, j);
      const int mn0 = min(e0, o0), mx0 = max(e0, o0);
      const int mn1 = min(e1, o1), mx1 = max(e1, o1);
      e0 = (up == lower) ? mn0 : mx0;
      e1 = (upHi == lower) ? mn1 : mx1;
    }
  }
  if (lane < cnt) colidx[row * KMAX + lane] = e0;
  if (lane + 64 < cnt) colidx[row * KMAX + lane + 64] = e1;
  cs[w][lane] = e0;
  cs[w][lane + 64] = e1;
  if (t < 64) sy[t >> 4][t & 15] = softy[(g * 4 + (t >> 4)) * C + (t & 15)];
  __syncthreads();
  // nbrsum for this wave's row (kept in LDS only)
  {
    const int cc = lane & 15, grp = lane >> 4;
    float acc = 0.f;
    for (int e = grp; e < cnt; e += 4)
      acc += softy[cs[w][e] * C + cc];
    acc += __shfl_xor(acc, 16);
    acc += __shfl_xor(acc, 32);
    if (lane < 16) nb[w][cc] = acc;
  }
  __syncthreads();
  // H partial for this group: thread (c,cp) over the group's 4 rows
  float hacc = 0.f;
  #pragma unroll
  for (int r = 0; r < 4; ++r)
    hacc = fmaf(nb[r][c], sy[r][cp], hacc);
  Hpart[(size_t)g * 272 + t] = hacc;
  if (cp == 0) {
    float dacc = 0.f;
    #pragma unroll
    for (int r = 0; r < 4; ++r)
      dacc += nb[r][c];
    Hpart[(size_t)g * 272 + 256 + c] = dacc;
  }
}

// ---------------- K4: H = Hun/d ; Q = rownorm((H H^T)*bias)  (2048 partials) -------------------
__global__ __launch_bounds__(256) void hq_final(const float* __restrict__ Hpart,
    const float* __restrict__ bias, float* __restrict__ H_out,
    float* __restrict__ Q_out, float* __restrict__ Qws) {
  __shared__ float Hs[256], Qs[256], rs[16], dd[16];
  const int t = threadIdx.x;
  const int c = t >> 4, cp = t & 15;
  float acc = 0.f;
  #pragma unroll 8
  for (int b = 0; b < HP; ++b) acc += Hpart[(size_t)b * 272 + t];
  if (t < 16) {
    float s = 0.f;
    #pragma unroll 8
    for (int b = 0; b < HP; ++b) s += Hpart[(size_t)b * 272 + 256 + t];
    dd[t] = s;
  }
  __syncthreads();
  const float Hv = acc / dd[c];
  Hs[t] = Hv;
  H_out[t] = Hv;
  __syncthreads();
  float q = 0.f;
  for (int k = 0; k < 16; ++k) q = fmaf(Hs[c * 16 + k], Hs[cp * 16 + k], q);
  q *= bias[t];
  Qs[t] = q;
  __syncthreads();
  if (t < 16) {
    float s = 0.f;
    for (int k = 0; k < 16; ++k) s += Qs[t * 16 + k];
    rs[t] = s;
  }
  __syncthreads();
  const float Qv = q / rs[c];
  Q_out[t] = Qv;
  Qws[t] = Qv;
}

// ---------------- K5: fused edge softmax + GCN layer1 (X1 bf16 gather) + X2 head ---------------
__global__ __launch_bounds__(256) void edge_gcn1(const float* __restrict__ Bmat,
    const float* __restrict__ Q, const int* __restrict__ rowcnt,
    const int* __restrict__ colidx, const unsigned short* __restrict__ X1b,
    const float* __restrict__ b1, const float* __restrict__ W2,
    float* __restrict__ gval, float* __restrict__ X2) {
  __shared__ float Prow[4][16];
  __shared__ float gv[4][128];
  __shared__ int cs[4][128];
  const int lane = threadIdx.x & 63, w = threadIdx.x >> 6;
  const int row = blockIdx.x * 4 + w;
  const int c = lane & 15, grp = lane >> 4;
  float acc = 0.f;
  for (int k = grp * 4; k < grp * 4 + 4; ++k)
    acc = fmaf(Bmat[row * C + k], Q[k * C + c], acc);
  acc += __shfl_xor(acc, 16);
  acc += __shfl_xor(acc, 32);
  if (lane < 16) Prow[w][c] = acc;
  __syncthreads();
  const int cnt = rowcnt[row];
  const int col0 = (lane < cnt) ? colidx[row * KMAX + lane] : 0;
  const int col1 = (lane + 64 < cnt) ? colidx[row * KMAX + lane + 64] : 0;
  float s0 = -1e30f, s1 = -1e30f;
  if (lane < cnt) {
    float s = 0.f;
    for (int k = 0; k < 16; ++k) s = fmaf(Prow[w][k], Bmat[col0 * C + k], s);
    s0 = s;
  }
  if (lane + 64 < cnt) {
    float s = 0.f;
    for (int k = 0; k < 16; ++k) s = fmaf(Prow[w][k], Bmat[col1 * C + k], s);
    s1 = s;
  }
  float m = fmaxf(s0, s1);
  for (int s = 1; s < 64; s <<= 1) m = fmaxf(m, __shfl_xor(m, s));
  const float e0 = __expf(s0 - m), e1 = __expf(s1 - m);
  float ssum = e0 + e1;
  for (int s = 1; s < 64; s <<= 1) ssum += __shfl_xor(ssum, s);
  const float inv = 1.f / ssum;
  const float g0 = e0 * inv, g1 = e1 * inv;
  if (lane < cnt) gval[row * KMAX + lane] = g0;
  if (lane + 64 < cnt) gval[row * KMAX + lane + 64] = g1;
  gv[w][lane] = g0; gv[w][lane + 64] = g1;
  cs[w][lane] = col0; cs[w][lane + 64] = col1;
  __syncthreads();
  float hacc = 0.f;
  for (int e = 0; e < cnt; ++e)
    hacc = fmaf(gv[w][e], b2f(X1b[(size_t)cs[w][e] * HG + lane]), hacc);
  const float h = fmaxf(hacc + b1[lane], 0.f);
  float x[16];
  #pragma unroll
  for (int cc = 0; cc < 16; ++cc) x[cc] = h * W2[lane * C + cc];
  #pragma unroll
  for (int s = 1; s < 64; s <<= 1)
    #pragma unroll
    for (int cc = 0; cc < 16; ++cc) x[cc] += __shfl_xor(x[cc], s);
  float v = x[0];
  #pragma unroll
  for (int cc = 1; cc < 16; ++cc) v = (lane == cc) ? x[cc] : v;
  if (lane < 16) X2[row * C + lane] = v;
}

// ---------------- K6: output = g @ X2 + b2 ; logits = softmax(output) --------------------------
__global__ __launch_bounds__(256) void gcn2(const float* __restrict__ X2,
    const float* __restrict__ b2, const int* __restrict__ rowcnt,
    const int* __restrict__ colidx, const float* __restrict__ gval,
    float* __restrict__ out_logits, float* __restrict__ out_output) {
  const int lane = threadIdx.x & 63;
  const int row = blockIdx.x * 4 + (threadIdx.x >> 6);
  const int c = lane & 15, grp = lane >> 4;
  const int cnt = rowcnt[row];
  float acc = 0.f;
  for (int e = grp; e < cnt; e += 4)
    acc = fmaf(gval[row * KMAX + e], X2[colidx[row * KMAX + e] * C + c], acc);
  acc += __shfl_xor(acc, 16);
  acc += __shfl_xor(acc, 32);
  acc += b2[c];
  float m = acc;
  for (int s = 1; s < 16; s <<= 1) m = fmaxf(m, __shfl_xor(m, s));
  const float e = __expf(acc - m);
  float ssum = e;
  for (int s = 1; s < 16; s <<= 1) ssum += __shfl_xor(ssum, s);
  if (lane < 16) {
    out_output[row * C + c] = acc;
    out_logits[row * C + c] = e / ssum;
  }
}

// ---------------- K7: losses (single block; launch boundary is the fence) ----------------------
__global__ __launch_bounds__(256) void loss_kernel(const float* __restrict__ logits,
    const float* __restrict__ Bmat, const int* __restrict__ idx,
    const int* __restrict__ label, float* __restrict__ out_loss) {
  __shared__ float sg[256], sm[256];
  const int t = threadIdx.x;
  float g = 0.f, m = 0.f;
  for (int i = t; i < 1024; i += 256) {
    const int ii = idx[i], ll = label[i];
    g -= logf(logits[ii * C + ll]);
    m -= logf(Bmat[ii * C + ll]);
  }
  sg[t] = g; sm[t] = m;
  __syncthreads();
  for (int s = 128; s > 0; s >>= 1) {
    if (t < s) { sg[t] += sg[t + s]; sm[t] += sm[t + s]; }
    __syncthreads();
  }
  if (t == 0) out_loss[0] = 1.0f * (sg[0] / 1024.f) + 1.0f * (sm[0] / 1024.f);
}

extern "C" void kernel_launch(void* const* d_in, const int* in_sizes, int n_in,
                              void* d_out, int out_size, void* d_ws, size_t ws_size,
                              hipStream_t stream) {
  const float* feature  = (const float*)d_in[0];
  const float* adj      = (const float*)d_in[1];
  const float* labels1h = (const float*)d_in[2];
  const float* bias     = (const float*)d_in[3];
  const float* Wm1 = (const float*)d_in[4];
  const float* bm1 = (const float*)d_in[5];
  const float* Wm2 = (const float*)d_in[6];
  const float* bm2 = (const float*)d_in[7];
  const float* W1  = (const float*)d_in[8];
  const float* b1  = (const float*)d_in[9];
  const float* W2  = (const float*)d_in[10];
  const float* b2  = (const float*)d_in[11];
  const int* idx   = (const int*)d_in[12];
  const int* label = (const int*)d_in[13];
  const int* mask  = (const int*)d_in[14];

  float* out = (float*)d_out;
  float* logits_o = out;                 // N*C
  float* loss_o   = out + (size_t)N * C; // 1
  float* H_o      = loss_o + 1;          // 256
  float* Q_o      = H_o + 256;           // 256
  float* outp_o   = Q_o + 256;           // N*C

  float* p = (float*)d_ws;
  float* Bmat   = p; p += (size_t)N * C;
  float* softy  = p; p += (size_t)N * C;
  float* X2     = p; p += (size_t)N * C;
  float* Hpart  = p; p += (size_t)HP * 272;
  float* Qws    = p; p += 256;
  int* rowcnt = (int*)p; p += N;
  int* colidx = (int*)p; p += (size_t)N * KMAX;
  float* gval = p; p += (size_t)N * KMAX;
  unsigned short* X1b   = (unsigned short*)p; p += (size_t)N * HG / 2;  // bf16
  unsigned short* Abf   = (unsigned short*)p;        // N*D bf16
  unsigned short* Wt    = Abf + (size_t)N * D;       // 320*512
  unsigned short* Wm2tb = Wt + 320 * 512;            // 16*256

  prep_kernel<<<(N * D / 8) / 256, 256, 0, stream>>>(feature, Wm1, W1, Wm2, Abf, Wt, Wm2tb, rowcnt);
  adj_tri<<<N / 4, 256, 0, stream>>>(adj, rowcnt, colidx);
  gemm_mlp<<<N / 32, 256, 0, stream>>>((const bf16x8*)Abf, (const bf16x8*)Wt, bm1,
      (const bf16x8*)Wm2tb, bm2, labels1h, mask, Bmat, softy, X1b);
  sort_nbr_h<<<HP, 256, 0, stream>>>(rowcnt, colidx, softy, Hpart);
  hq_final<<<1, 256, 0, stream>>>(Hpart, bias, H_o, Q_o, Qws);
  edge_gcn1<<<N / 4, 256, 0, stream>>>(Bmat, Qws, rowcnt, colidx, X1b, b1, W2, gval, X2);
  gcn2<<<N / 4, 256, 0, stream>>>(X2, b2, rowcnt, colidx, gval, logits_o, outp_o);
  loss_kernel<<<1, 256, 0, stream>>>(logits_o, Bmat, idx, label, loss_o);
}

// Round 14
// 142.432 us; speedup vs baseline: 1.8650x; 1.8650x over previous
//
#include <hip/hip_runtime.h>
#include <math.h>

#define N   8192
#define D   512
#define C   16
#define HM  256
#define HG  64
#define KMAX 128   // max neighbors per row (mean ~65, 12-sigma safe)

typedef __attribute__((ext_vector_type(8))) short bf16x8;
typedef __attribute__((ext_vector_type(4))) float f32x4;
typedef unsigned long long ull;

__device__ __forceinline__ unsigned short f2b(float x) {
  union { float f; unsigned int u; } v; v.f = x;
  unsigned int r = v.u + 0x7FFFu + ((v.u >> 16) & 1u);  // RNE
  return (unsigned short)(r >> 16);
}
__device__ __forceinline__ float b2f(unsigned short b) {
  union { unsigned int u; float f; } v; v.u = ((unsigned int)b) << 16;
  return v.f;
}

// ---------------- K0: prep: feature->bf16, Wcat->bf16 T, Wm2->bf16 T ---------------------------
__global__ __launch_bounds__(256) void prep_kernel(const float* __restrict__ feat,
    const float* __restrict__ Wm1, const float* __restrict__ W1,
    const float* __restrict__ Wm2, unsigned short* __restrict__ Abf,
    unsigned short* __restrict__ Wt, unsigned short* __restrict__ Wm2tb) {
  const int tid = blockIdx.x * 256 + threadIdx.x;  // 524288 threads
  const float4 a = *(const float4*)&feat[(size_t)tid * 8];
  const float4 b = *(const float4*)&feat[(size_t)tid * 8 + 4];
  ushort4 lo, hi;
  lo.x = f2b(a.x); lo.y = f2b(a.y); lo.z = f2b(a.z); lo.w = f2b(a.w);
  hi.x = f2b(b.x); hi.y = f2b(b.y); hi.z = f2b(b.z); hi.w = f2b(b.w);
  *(ushort4*)&Abf[(size_t)tid * 8] = lo;
  *(ushort4*)&Abf[(size_t)tid * 8 + 4] = hi;
  if (tid < 320 * 512) {  // Wt[n][k]
    const int n = tid >> 9, k = tid & 511;
    const float v = (n < 256) ? Wm1[k * 256 + n] : W1[k * 64 + (n - 256)];
    Wt[tid] = f2b(v);
  }
  if (tid < 16 * 256) {   // Wm2tb[c][k] = Wm2[k][c]
    const int cc = tid >> 8, k = tid & 255;
    Wm2tb[tid] = f2b(Wm2[k * 16 + cc]);
  }
}

// ---------------- K1: upper-triangle tiles -> full bitmask (branchless stream + ballot) --------
// grid (128,128); block handles 64x64 tile (I=blockIdx.y, J=blockIdx.x); J<I exits (symmetry).
__global__ __launch_bounds__(256) void tile_ballot(const float* __restrict__ adj,
    ull* __restrict__ bm) {
  const int I = blockIdx.y, J = blockIdx.x;
  if (J < I) return;
  __shared__ unsigned char tb[64][68];
  const int t = threadIdx.x;
  #pragma unroll
  for (int rr = 0; rr < 4; ++rr) {
    const int r = rr * 16 + (t >> 4);
    const int c = (t & 15) * 4;
    const float4 v = *(const float4*)&adj[(size_t)(I * 64 + r) * N + J * 64 + c];
    tb[r][c + 0] = v.x > 0.f;
    tb[r][c + 1] = v.y > 0.f;
    tb[r][c + 2] = v.z > 0.f;
    tb[r][c + 3] = v.w > 0.f;
  }
  __syncthreads();
  const int lane = t & 63, w = t >> 6;
  #pragma unroll
  for (int i = 0; i < 16; ++i) {
    const int r = w * 16 + i;
    // row word: bit l = adj[I*64+r][J*64+l]  -> bm[I*64+r][word J]
    const ull rw = __ballot(tb[r][lane] != 0);
    if (lane == 0) bm[(size_t)(I * 64 + r) * 128 + J] = rw;
    // col word: bit l = adj[I*64+l][J*64+r] == adj[J*64+r][I*64+l] -> bm[J*64+r][word I]
    const ull cw = __ballot(tb[lane][r] != 0);
    if (lane == 0) bm[(size_t)(J * 64 + r) * 128 + I] = cw;
  }
}

// ---------------- K2: GEMM (BM=32, 256 blocks) + MLP layer2 + softmax; X1 stored bf16 ----------
__global__ __launch_bounds__(256) void gemm_mlp(
    const bf16x8* __restrict__ Abf, const bf16x8* __restrict__ Wt,
    const float* __restrict__ bm1, const bf16x8* __restrict__ Wm2tb,
    const float* __restrict__ bm2, const float* __restrict__ labels1h,
    const int* __restrict__ mask, float* __restrict__ Bmat,
    float* __restrict__ softy, unsigned short* __restrict__ X1b) {
  __shared__ unsigned short c1[32][264];   // bf16 C1 tile (row stride 528B)
  const int l = threadIdx.x & 63, w = threadIdx.x >> 6;
  const int m0 = blockIdx.x * 32;
  const int kb = l >> 4, cl = l & 15;
  const int rw = (w >> 1) * 16;          // row half: 0 or 16
  const int nt0 = (w & 1) * 10;          // tile half: 0..9 or 10..19
  const int row = m0 + rw + cl;
  const bf16x8* arow = Abf + (size_t)row * 64 + kb;
  f32x4 acc[10] = {};
  for (int kk = 0; kk < 16; ++kk) {
    const bf16x8 af = arow[kk * 4];
    #pragma unroll
    for (int i = 0; i < 10; ++i) {
      const bf16x8 bfr = Wt[(size_t)((nt0 + i) * 16 + cl) * 64 + kk * 4 + kb];
      acc[i] = __builtin_amdgcn_mfma_f32_16x16x32_bf16(af, bfr, acc[i], 0, 0, 0);
    }
  }
  // epilogue: C/D layout col=l&15, row=(l>>4)*4+r
  const int rl0 = rw + kb * 4;
  #pragma unroll
  for (int i = 0; i < 10; ++i) {
    const int nt = nt0 + i;
    const int col = nt * 16 + cl;
    if (nt < 16) {
      const float bv = bm1[col];
      #pragma unroll
      for (int r = 0; r < 4; ++r)
        c1[rl0 + r][col] = f2b(fmaxf(acc[i][r] + bv, 0.f));
    } else {
      const int xc = col - 256;
      #pragma unroll
      for (int r = 0; r < 4; ++r)
        X1b[(size_t)(m0 + rl0 + r) * HG + xc] = f2b(acc[i][r]);
    }
  }
  __syncthreads();
  // layer 2 (waves 0,2): B = softmax(C1 @ Wm2 + bm2) for rows m0+rw..+15
  if ((w & 1) == 0) {
    f32x4 acc2 = {0.f, 0.f, 0.f, 0.f};
    #pragma unroll
    for (int kk = 0; kk < 8; ++kk) {
      const bf16x8 a2 = *(const bf16x8*)&c1[rw + cl][kk * 32 + kb * 8];
      const bf16x8 b2v = Wm2tb[(size_t)cl * 32 + kk * 4 + kb];
      acc2 = __builtin_amdgcn_mfma_f32_16x16x32_bf16(a2, b2v, acc2, 0, 0, 0);
    }
    const float bm2v = bm2[cl];
    #pragma unroll
    for (int r = 0; r < 4; ++r) {
      float v = acc2[r] + bm2v;
      float m = v;
      #pragma unroll
      for (int s = 1; s < 16; s <<= 1) m = fmaxf(m, __shfl_xor(m, s));
      const float e = __expf(v - m);
      float ssum = e;
      #pragma unroll
      for (int s = 1; s < 16; s <<= 1) ssum += __shfl_xor(ssum, s);
      const float bb = e / ssum;
      const int grow = m0 + rw + kb * 4 + r;
      Bmat[grow * C + cl] = bb;
      softy[grow * C + cl] = mask[grow] ? labels1h[grow * C + cl] : bb;
    }
  }
}

// ---------------- K3: bitmask -> sorted ELL (no atomics, deterministic) + nbrsum ---------------
__global__ __launch_bounds__(256) void extract_nbr(const ull* __restrict__ bm,
    int* __restrict__ rowcnt, int* __restrict__ colidx,
    const float* __restrict__ softy, float* __restrict__ nbrsum) {
  __shared__ int cs[4][128];
  const int t = threadIdx.x, lane = t & 63, w = t >> 6;
  const int row = blockIdx.x * 4 + w;
  const ull w0 = bm[(size_t)row * 128 + lane];        // words 0..63  (cols 64*lane+b)
  const ull w1 = bm[(size_t)row * 128 + 64 + lane];   // words 64..127
  const int c0 = __builtin_popcountll(w0);
  const int c1 = __builtin_popcountll(w1);
  int s0 = c0, s1 = c1;
  #pragma unroll
  for (int s = 1; s < 64; s <<= 1) {
    const int y0 = __shfl_up(s0, s);
    const int y1 = __shfl_up(s1, s);
    if (lane >= s) { s0 += y0; s1 += y1; }
  }
  const int total0 = __shfl(s0, 63);
  const int total = total0 + __shfl(s1, 63);
  // decode word half 0 (sorted: word index = lane)
  int off = s0 - c0;
  ull x = w0;
  while (x) {
    const int b = __builtin_ctzll(x);
    if (off < KMAX) {
      const int col = lane * 64 + b;
      colidx[(size_t)row * KMAX + off] = col;
      cs[w][off] = col;
    }
    ++off;
    x &= x - 1;
  }
  // decode word half 1
  off = total0 + s1 - c1;
  x = w1;
  while (x) {
    const int b = __builtin_ctzll(x);
    if (off < KMAX) {
      const int col = (64 + lane) * 64 + b;
      colidx[(size_t)row * KMAX + off] = col;
      cs[w][off] = col;
    }
    ++off;
    x &= x - 1;
  }
  const int cnt = min(total, KMAX);
  if (lane == 0) rowcnt[row] = cnt;
  __syncthreads();
  // nbrsum[row,:] = sum over neighbors of softy
  const int cc = lane & 15, grp = lane >> 4;
  float acc = 0.f;
  for (int e = grp; e < cnt; e += 4)
    acc += softy[cs[w][e] * C + cc];
  acc += __shfl_xor(acc, 16);
  acc += __shfl_xor(acc, 32);
  if (lane < 16) nbrsum[row * C + cc] = acc;
}

// ---------------- K4a: partial H[c,c'] and d[c] over row slices (64 blocks, R9-proven) ---------
__global__ __launch_bounds__(256) void h_partial(const float* __restrict__ nbrsum,
    const float* __restrict__ softy, float* __restrict__ Hpart) {
  const int t = threadIdx.x;
  const int c = t >> 4, cp = t & 15;
  float acc = 0.f, dacc = 0.f;
  const int j0 = blockIdx.x * (N / 64);
  for (int j = j0; j < j0 + N / 64; ++j) {
    const float nv = nbrsum[j * C + c];
    acc = fmaf(nv, softy[j * C + cp], acc);
    if (cp == 0) dacc += nv;
  }
  Hpart[blockIdx.x * 272 + t] = acc;
  if (cp == 0) Hpart[blockIdx.x * 272 + 256 + c] = dacc;
}

// ---------------- K4b: H = Hun/d ; Q = rownorm((H H^T)*bias)  (64 partials) --------------------
__global__ __launch_bounds__(256) void hq_final(const float* __restrict__ Hpart,
    const float* __restrict__ bias, float* __restrict__ H_out,
    float* __restrict__ Q_out, float* __restrict__ Qws) {
  __shared__ float Hs[256], Qs[256], rs[16], dd[16];
  const int t = threadIdx.x;
  const int c = t >> 4, cp = t & 15;
  float acc = 0.f;
  for (int b = 0; b < 64; ++b) acc += Hpart[b * 272 + t];
  if (t < 16) {
    float s = 0.f;
    for (int b = 0; b < 64; ++b) s += Hpart[b * 272 + 256 + t];
    dd[t] = s;
  }
  __syncthreads();
  const float Hv = acc / dd[c];
  Hs[t] = Hv;
  H_out[t] = Hv;
  __syncthreads();
  float q = 0.f;
  for (int k = 0; k < 16; ++k) q = fmaf(Hs[c * 16 + k], Hs[cp * 16 + k], q);
  q *= bias[t];
  Qs[t] = q;
  __syncthreads();
  if (t < 16) {
    float s = 0.f;
    for (int k = 0; k < 16; ++k) s += Qs[t * 16 + k];
    rs[t] = s;
  }
  __syncthreads();
  const float Qv = q / rs[c];
  Q_out[t] = Qv;
  Qws[t] = Qv;
}

// ---------------- K5: fused edge softmax + GCN layer1 (X1 bf16 gather) + X2 head ---------------
__global__ __launch_bounds__(256) void edge_gcn1(const float* __restrict__ Bmat,
    const float* __restrict__ Q, const int* __restrict__ rowcnt,
    const int* __restrict__ colidx, const unsigned short* __restrict__ X1b,
    const float* __restrict__ b1, const float* __restrict__ W2,
    float* __restrict__ gval, float* __restrict__ X2) {
  __shared__ float Prow[4][16];
  __shared__ float gv[4][128];
  __shared__ int cs[4][128];
  const int lane = threadIdx.x & 63, w = threadIdx.x >> 6;
  const int row = blockIdx.x * 4 + w;
  const int c = lane & 15, grp = lane >> 4;
  float acc = 0.f;
  for (int k = grp * 4; k < grp * 4 + 4; ++k)
    acc = fmaf(Bmat[row * C + k], Q[k * C + c], acc);
  acc += __shfl_xor(acc, 16);
  acc += __shfl_xor(acc, 32);
  if (lane < 16) Prow[w][c] = acc;
  __syncthreads();
  const int cnt = rowcnt[row];
  const int col0 = (lane < cnt) ? colidx[row * KMAX + lane] : 0;
  const int col1 = (lane + 64 < cnt) ? colidx[row * KMAX + lane + 64] : 0;
  float s0 = -1e30f, s1 = -1e30f;
  if (lane < cnt) {
    float s = 0.f;
    for (int k = 0; k < 16; ++k) s = fmaf(Prow[w][k], Bmat[col0 * C + k], s);
    s0 = s;
  }
  if (lane + 64 < cnt) {
    float s = 0.f;
    for (int k = 0; k < 16; ++k) s = fmaf(Prow[w][k], Bmat[col1 * C + k], s);
    s1 = s;
  }
  float m = fmaxf(s0, s1);
  for (int s = 1; s < 64; s <<= 1) m = fmaxf(m, __shfl_xor(m, s));
  const float e0 = __expf(s0 - m), e1 = __expf(s1 - m);
  float ssum = e0 + e1;
  for (int s = 1; s < 64; s <<= 1) ssum += __shfl_xor(ssum, s);
  const float inv = 1.f / ssum;
  const float g0 = e0 * inv, g1 = e1 * inv;
  if (lane < cnt) gval[row * KMAX + lane] = g0;
  if (lane + 64 < cnt) gval[row * KMAX + lane + 64] = g1;
  gv[w][lane] = g0; gv[w][lane + 64] = g1;
  cs[w][lane] = col0; cs[w][lane + 64] = col1;
  __syncthreads();
  float hacc = 0.f;
  for (int e = 0; e < cnt; ++e)
    hacc = fmaf(gv[w][e], b2f(X1b[(size_t)cs[w][e] * HG + lane]), hacc);
  const float h = fmaxf(hacc + b1[lane], 0.f);
  float x[16];
  #pragma unroll
  for (int cc = 0; cc < 16; ++cc) x[cc] = h * W2[lane * C + cc];
  #pragma unroll
  for (int s = 1; s < 64; s <<= 1)
    #pragma unroll
    for (int cc = 0; cc < 16; ++cc) x[cc] += __shfl_xor(x[cc], s);
  float v = x[0];
  #pragma unroll
  for (int cc = 1; cc < 16; ++cc) v = (lane == cc) ? x[cc] : v;
  if (lane < 16) X2[row * C + lane] = v;
}

// ---------------- K6: output = g @ X2 + b2 ; logits = softmax(output) --------------------------
__global__ __launch_bounds__(256) void gcn2(const float* __restrict__ X2,
    const float* __restrict__ b2, const int* __restrict__ rowcnt,
    const int* __restrict__ colidx, const float* __restrict__ gval,
    float* __restrict__ out_logits, float* __restrict__ out_output) {
  const int lane = threadIdx.x & 63;
  const int row = blockIdx.x * 4 + (threadIdx.x >> 6);
  const int c = lane & 15, grp = lane >> 4;
  const int cnt = rowcnt[row];
  float acc = 0.f;
  for (int e = grp; e < cnt; e += 4)
    acc = fmaf(gval[row * KMAX + e], X2[colidx[row * KMAX + e] * C + c], acc);
  acc += __shfl_xor(acc, 16);
  acc += __shfl_xor(acc, 32);
  acc += b2[c];
  float m = acc;
  for (int s = 1; s < 16; s <<= 1) m = fmaxf(m, __shfl_xor(m, s));
  const float e = __expf(acc - m);
  float ssum = e;
  for (int s = 1; s < 16; s <<= 1) ssum += __shfl_xor(ssum, s);
  if (lane < 16) {
    out_output[row * C + c] = acc;
    out_logits[row * C + c] = e / ssum;
  }
}

// ---------------- K7: losses (single block; launch boundary is the fence) ----------------------
__global__ __launch_bounds__(256) void loss_kernel(const float* __restrict__ logits,
    const float* __restrict__ Bmat, const int* __restrict__ idx,
    const int* __restrict__ label, float* __restrict__ out_loss) {
  __shared__ float sg[256], sm[256];
  const int t = threadIdx.x;
  float g = 0.f, m = 0.f;
  for (int i = t; i < 1024; i += 256) {
    const int ii = idx[i], ll = label[i];
    g -= logf(logits[ii * C + ll]);
    m -= logf(Bmat[ii * C + ll]);
  }
  sg[t] = g; sm[t] = m;
  __syncthreads();
  for (int s = 128; s > 0; s >>= 1) {
    if (t < s) { sg[t] += sg[t + s]; sm[t] += sm[t + s]; }
    __syncthreads();
  }
  if (t == 0) out_loss[0] = 1.0f * (sg[0] / 1024.f) + 1.0f * (sm[0] / 1024.f);
}

extern "C" void kernel_launch(void* const* d_in, const int* in_sizes, int n_in,
                              void* d_out, int out_size, void* d_ws, size_t ws_size,
                              hipStream_t stream) {
  const float* feature  = (const float*)d_in[0];
  const float* adj      = (const float*)d_in[1];
  const float* labels1h = (const float*)d_in[2];
  const float* bias     = (const float*)d_in[3];
  const float* Wm1 = (const float*)d_in[4];
  const float* bm1 = (const float*)d_in[5];
  const float* Wm2 = (const float*)d_in[6];
  const float* bm2 = (const float*)d_in[7];
  const float* W1  = (const float*)d_in[8];
  const float* b1  = (const float*)d_in[9];
  const float* W2  = (const float*)d_in[10];
  const float* b2  = (const float*)d_in[11];
  const int* idx   = (const int*)d_in[12];
  const int* label = (const int*)d_in[13];
  const int* mask  = (const int*)d_in[14];

  float* out = (float*)d_out;
  float* logits_o = out;                 // N*C
  float* loss_o   = out + (size_t)N * C; // 1
  float* H_o      = loss_o + 1;          // 256
  float* Q_o      = H_o + 256;           // 256
  float* outp_o   = Q_o + 256;           // N*C

  float* p = (float*)d_ws;
  float* Bmat   = p; p += (size_t)N * C;
  float* softy  = p; p += (size_t)N * C;
  float* nbrsum = p; p += (size_t)N * C;
  float* X2     = p; p += (size_t)N * C;
  float* Hpart  = p; p += 64 * 272;
  float* Qws    = p; p += 256;
  int* rowcnt = (int*)p; p += N;
  int* colidx = (int*)p; p += (size_t)N * KMAX;
  float* gval = p; p += (size_t)N * KMAX;
  unsigned short* X1b   = (unsigned short*)p; p += (size_t)N * HG / 2;  // bf16
  unsigned short* Abf   = (unsigned short*)p; p += (size_t)N * D / 2;   // bf16
  unsigned short* Wt    = (unsigned short*)p; p += 320 * 512 / 2;
  unsigned short* Wm2tb = (unsigned short*)p; p += 16 * 256 / 2;
  ull* bm = (ull*)p;                              // N*128 u64 = 8 MB

  prep_kernel<<<(N * D / 8) / 256, 256, 0, stream>>>(feature, Wm1, W1, Wm2, Abf, Wt, Wm2tb);
  tile_ballot<<<dim3(128, 128), 256, 0, stream>>>(adj, bm);
  gemm_mlp<<<N / 32, 256, 0, stream>>>((const bf16x8*)Abf, (const bf16x8*)Wt, bm1,
      (const bf16x8*)Wm2tb, bm2, labels1h, mask, Bmat, softy, X1b);
  extract_nbr<<<N / 4, 256, 0, stream>>>(bm, rowcnt, colidx, softy, nbrsum);
  h_partial<<<64, 256, 0, stream>>>(nbrsum, softy, Hpart);
  hq_final<<<1, 256, 0, stream>>>(Hpart, bias, H_o, Q_o, Qws);
  edge_gcn1<<<N / 4, 256, 0, stream>>>(Bmat, Qws, rowcnt, colidx, X1b, b1, W2, gval, X2);
  gcn2<<<N / 4, 256, 0, stream>>>(X2, b2, rowcnt, colidx, gval, logits_o, outp_o);
  loss_kernel<<<1, 256, 0, stream>>>(logits_o, Bmat, idx, label, loss_o);
}

// Round 15
// 126.945 us; speedup vs baseline: 2.0926x; 1.1220x over previous
//
#include <hip/hip_runtime.h>
#include <math.h>

#define N   8192
#define D   512
#define C   16
#define HM  256
#define HG  64
#define KMAX 128   // max neighbors per row (mean ~65, 12-sigma safe)

typedef __attribute__((ext_vector_type(8))) short bf16x8;
typedef __attribute__((ext_vector_type(4))) float f32x4;
typedef unsigned long long ull;

__device__ __forceinline__ unsigned short f2b(float x) {
  union { float f; unsigned int u; } v; v.f = x;
  unsigned int r = v.u + 0x7FFFu + ((v.u >> 16) & 1u);  // RNE
  return (unsigned short)(r >> 16);
}
__device__ __forceinline__ float b2f(unsigned short b) {
  union { unsigned int u; float f; } v; v.u = ((unsigned int)b) << 16;
  return v.f;
}

// ---------------- K1: exact-triangle tile ballot + weight prep (grid 129 x 65) -----------------
// y<64: 64x64 adj tile, triangular map (8256 blocks, no idle). y==64: weight conversion.
__global__ __launch_bounds__(256) void tile_ballot(const float* __restrict__ adj,
    ull* __restrict__ bm, const float* __restrict__ Wm1, const float* __restrict__ W1,
    const float* __restrict__ Wm2, unsigned short* __restrict__ Wt,
    unsigned short* __restrict__ Wm2tb) {
  const int t = threadIdx.x;
  if (blockIdx.y == 64) {   // ---- weight prep: 129 blocks ----
    const int start = blockIdx.x * 256 + t;
    for (int i = start; i < 320 * 512; i += 129 * 256) {
      const int n = i >> 9, k = i & 511;
      Wt[i] = f2b((n < 256) ? Wm1[k * 256 + n] : W1[k * 64 + (n - 256)]);
    }
    for (int i = start; i < 16 * 256; i += 129 * 256) {
      const int cc = i >> 8, k = i & 255;
      Wm2tb[i] = f2b(Wm2[k * 16 + cc]);
    }
    return;
  }
  // rectangle (129 x 64) -> upper triangle (I<=J), exact cover
  const int p = blockIdx.y;
  int I, J;
  if ((int)blockIdx.x < 128 - p) { I = p; J = p + blockIdx.x; }
  else                           { I = 127 - p; J = blockIdx.x - 1; }
  __shared__ unsigned char tb[64][68];
  #pragma unroll
  for (int rr = 0; rr < 4; ++rr) {
    const int r = rr * 16 + (t >> 4);
    const int c = (t & 15) * 4;
    const float4 v = *(const float4*)&adj[(size_t)(I * 64 + r) * N + J * 64 + c];
    tb[r][c + 0] = v.x > 0.f;
    tb[r][c + 1] = v.y > 0.f;
    tb[r][c + 2] = v.z > 0.f;
    tb[r][c + 3] = v.w > 0.f;
  }
  __syncthreads();
  const int lane = t & 63, w = t >> 6;
  #pragma unroll
  for (int i = 0; i < 16; ++i) {
    const int r = w * 16 + i;
    const ull rw = __ballot(tb[r][lane] != 0);      // row word -> bm[I*64+r][J]
    if (lane == 0) bm[(size_t)(I * 64 + r) * 128 + J] = rw;
    const ull cw = __ballot(tb[lane][r] != 0);      // col word -> bm[J*64+r][I] (symmetry)
    if (lane == 0) bm[(size_t)(J * 64 + r) * 128 + I] = cw;
  }
}

// ---------------- K2: GEMM (BM=32, 256 blocks, A converted on the fly) + MLP + softmax ---------
__global__ __launch_bounds__(256) void gemm_mlp(
    const float* __restrict__ feature, const bf16x8* __restrict__ Wt,
    const float* __restrict__ bm1, const bf16x8* __restrict__ Wm2tb,
    const float* __restrict__ bm2, const float* __restrict__ labels1h,
    const int* __restrict__ mask, float* __restrict__ Bmat,
    float* __restrict__ softy, unsigned short* __restrict__ X1b) {
  __shared__ unsigned short c1[32][264];   // bf16 C1 tile (row stride 528B)
  const int l = threadIdx.x & 63, w = threadIdx.x >> 6;
  const int m0 = blockIdx.x * 32;
  const int kb = l >> 4, cl = l & 15;
  const int rw = (w >> 1) * 16;          // row half: 0 or 16
  const int nt0 = (w & 1) * 10;          // tile half: 0..9 or 10..19
  const int row = m0 + rw + cl;
  const float* arow = feature + (size_t)row * D + kb * 8;
  f32x4 acc[10] = {};
  for (int kk = 0; kk < 16; ++kk) {
    const float4 a0 = *(const float4*)&arow[kk * 32];
    const float4 a1 = *(const float4*)&arow[kk * 32 + 4];
    bf16x8 af;
    af[0] = f2b(a0.x); af[1] = f2b(a0.y); af[2] = f2b(a0.z); af[3] = f2b(a0.w);
    af[4] = f2b(a1.x); af[5] = f2b(a1.y); af[6] = f2b(a1.z); af[7] = f2b(a1.w);
    #pragma unroll
    for (int i = 0; i < 10; ++i) {
      const bf16x8 bfr = Wt[(size_t)((nt0 + i) * 16 + cl) * 64 + kk * 4 + kb];
      acc[i] = __builtin_amdgcn_mfma_f32_16x16x32_bf16(af, bfr, acc[i], 0, 0, 0);
    }
  }
  // epilogue: C/D layout col=l&15, row=(l>>4)*4+r
  const int rl0 = rw + kb * 4;
  #pragma unroll
  for (int i = 0; i < 10; ++i) {
    const int nt = nt0 + i;
    const int col = nt * 16 + cl;
    if (nt < 16) {
      const float bv = bm1[col];
      #pragma unroll
      for (int r = 0; r < 4; ++r)
        c1[rl0 + r][col] = f2b(fmaxf(acc[i][r] + bv, 0.f));
    } else {
      const int xc = col - 256;
      #pragma unroll
      for (int r = 0; r < 4; ++r)
        X1b[(size_t)(m0 + rl0 + r) * HG + xc] = f2b(acc[i][r]);
    }
  }
  __syncthreads();
  // layer 2 (waves 0,2): B = softmax(C1 @ Wm2 + bm2) for rows m0+rw..+15
  if ((w & 1) == 0) {
    f32x4 acc2 = {0.f, 0.f, 0.f, 0.f};
    #pragma unroll
    for (int kk = 0; kk < 8; ++kk) {
      const bf16x8 a2 = *(const bf16x8*)&c1[rw + cl][kk * 32 + kb * 8];
      const bf16x8 b2v = Wm2tb[(size_t)cl * 32 + kk * 4 + kb];
      acc2 = __builtin_amdgcn_mfma_f32_16x16x32_bf16(a2, b2v, acc2, 0, 0, 0);
    }
    const float bm2v = bm2[cl];
    #pragma unroll
    for (int r = 0; r < 4; ++r) {
      float v = acc2[r] + bm2v;
      float m = v;
      #pragma unroll
      for (int s = 1; s < 16; s <<= 1) m = fmaxf(m, __shfl_xor(m, s));
      const float e = __expf(v - m);
      float ssum = e;
      #pragma unroll
      for (int s = 1; s < 16; s <<= 1) ssum += __shfl_xor(ssum, s);
      const float bb = e / ssum;
      const int grow = m0 + rw + kb * 4 + r;
      Bmat[grow * C + cl] = bb;
      softy[grow * C + cl] = mask[grow] ? labels1h[grow * C + cl] : bb;
    }
  }
}

// ---------------- K3: bitmask -> sorted ELL (no atomics, deterministic) + nbrsum ---------------
__global__ __launch_bounds__(256) void extract_nbr(const ull* __restrict__ bm,
    int* __restrict__ rowcnt, int* __restrict__ colidx,
    const float* __restrict__ softy, float* __restrict__ nbrsum) {
  __shared__ int cs[4][128];
  const int t = threadIdx.x, lane = t & 63, w = t >> 6;
  const int row = blockIdx.x * 4 + w;
  const ull w0 = bm[(size_t)row * 128 + lane];        // words 0..63
  const ull w1 = bm[(size_t)row * 128 + 64 + lane];   // words 64..127
  const int c0 = __builtin_popcountll(w0);
  const int c1 = __builtin_popcountll(w1);
  int s0 = c0, s1 = c1;
  #pragma unroll
  for (int s = 1; s < 64; s <<= 1) {
    const int y0 = __shfl_up(s0, s);
    const int y1 = __shfl_up(s1, s);
    if (lane >= s) { s0 += y0; s1 += y1; }
  }
  const int total0 = __shfl(s0, 63);
  const int total = total0 + __shfl(s1, 63);
  int off = s0 - c0;
  ull x = w0;
  while (x) {
    const int b = __builtin_ctzll(x);
    if (off < KMAX) {
      const int col = lane * 64 + b;
      colidx[(size_t)row * KMAX + off] = col;
      cs[w][off] = col;
    }
    ++off;
    x &= x - 1;
  }
  off = total0 + s1 - c1;
  x = w1;
  while (x) {
    const int b = __builtin_ctzll(x);
    if (off < KMAX) {
      const int col = (64 + lane) * 64 + b;
      colidx[(size_t)row * KMAX + off] = col;
      cs[w][off] = col;
    }
    ++off;
    x &= x - 1;
  }
  const int cnt = min(total, KMAX);
  if (lane == 0) rowcnt[row] = cnt;
  __syncthreads();
  const int cc = lane & 15, grp = lane >> 4;
  float acc = 0.f;
  for (int e = grp; e < cnt; e += 4)
    acc += softy[cs[w][e] * C + cc];
  acc += __shfl_xor(acc, 16);
  acc += __shfl_xor(acc, 32);
  if (lane < 16) nbrsum[row * C + cc] = acc;
}

// ---------------- K4a: partial H[c,c'] and d[c] over row slices (64 blocks) --------------------
__global__ __launch_bounds__(256) void h_partial(const float* __restrict__ nbrsum,
    const float* __restrict__ softy, float* __restrict__ Hpart) {
  const int t = threadIdx.x;
  const int c = t >> 4, cp = t & 15;
  float acc = 0.f, dacc = 0.f;
  const int j0 = blockIdx.x * (N / 64);
  for (int j = j0; j < j0 + N / 64; ++j) {
    const float nv = nbrsum[j * C + c];
    acc = fmaf(nv, softy[j * C + cp], acc);
    if (cp == 0) dacc += nv;
  }
  Hpart[blockIdx.x * 272 + t] = acc;
  if (cp == 0) Hpart[blockIdx.x * 272 + 256 + c] = dacc;
}

// ---------------- K4b: H = Hun/d ; Q = rownorm((H H^T)*bias)  (64 partials) --------------------
__global__ __launch_bounds__(256) void hq_final(const float* __restrict__ Hpart,
    const float* __restrict__ bias, float* __restrict__ H_out,
    float* __restrict__ Q_out, float* __restrict__ Qws) {
  __shared__ float Hs[256], Qs[256], rs[16], dd[16];
  const int t = threadIdx.x;
  const int c = t >> 4, cp = t & 15;
  float acc = 0.f;
  for (int b = 0; b < 64; ++b) acc += Hpart[b * 272 + t];
  if (t < 16) {
    float s = 0.f;
    for (int b = 0; b < 64; ++b) s += Hpart[b * 272 + 256 + t];
    dd[t] = s;
  }
  __syncthreads();
  const float Hv = acc / dd[c];
  Hs[t] = Hv;
  H_out[t] = Hv;
  __syncthreads();
  float q = 0.f;
  for (int k = 0; k < 16; ++k) q = fmaf(Hs[c * 16 + k], Hs[cp * 16 + k], q);
  q *= bias[t];
  Qs[t] = q;
  __syncthreads();
  if (t < 16) {
    float s = 0.f;
    for (int k = 0; k < 16; ++k) s += Qs[t * 16 + k];
    rs[t] = s;
  }
  __syncthreads();
  const float Qv = q / rs[c];
  Q_out[t] = Qv;
  Qws[t] = Qv;
}

// ---------------- K5: fused edge softmax + GCN layer1 (X1 bf16 gather) + X2 head ---------------
__global__ __launch_bounds__(256) void edge_gcn1(const float* __restrict__ Bmat,
    const float* __restrict__ Q, const int* __restrict__ rowcnt,
    const int* __restrict__ colidx, const unsigned short* __restrict__ X1b,
    const float* __restrict__ b1, const float* __restrict__ W2,
    float* __restrict__ gval, float* __restrict__ X2) {
  __shared__ float Prow[4][16];
  __shared__ float gv[4][128];
  __shared__ int cs[4][128];
  const int lane = threadIdx.x & 63, w = threadIdx.x >> 6;
  const int row = blockIdx.x * 4 + w;
  const int c = lane & 15, grp = lane >> 4;
  float acc = 0.f;
  for (int k = grp * 4; k < grp * 4 + 4; ++k)
    acc = fmaf(Bmat[row * C + k], Q[k * C + c], acc);
  acc += __shfl_xor(acc, 16);
  acc += __shfl_xor(acc, 32);
  if (lane < 16) Prow[w][c] = acc;
  __syncthreads();
  const int cnt = rowcnt[row];
  const int col0 = (lane < cnt) ? colidx[row * KMAX + lane] : 0;
  const int col1 = (lane + 64 < cnt) ? colidx[row * KMAX + lane + 64] : 0;
  float s0 = -1e30f, s1 = -1e30f;
  if (lane < cnt) {
    float s = 0.f;
    for (int k = 0; k < 16; ++k) s = fmaf(Prow[w][k], Bmat[col0 * C + k], s);
    s0 = s;
  }
  if (lane + 64 < cnt) {
    float s = 0.f;
    for (int k = 0; k < 16; ++k) s = fmaf(Prow[w][k], Bmat[col1 * C + k], s);
    s1 = s;
  }
  float m = fmaxf(s0, s1);
  for (int s = 1; s < 64; s <<= 1) m = fmaxf(m, __shfl_xor(m, s));
  const float e0 = __expf(s0 - m), e1 = __expf(s1 - m);
  float ssum = e0 + e1;
  for (int s = 1; s < 64; s <<= 1) ssum += __shfl_xor(ssum, s);
  const float inv = 1.f / ssum;
  const float g0 = e0 * inv, g1 = e1 * inv;
  if (lane < cnt) gval[row * KMAX + lane] = g0;
  if (lane + 64 < cnt) gval[row * KMAX + lane + 64] = g1;
  gv[w][lane] = g0; gv[w][lane + 64] = g1;
  cs[w][lane] = col0; cs[w][lane + 64] = col1;
  __syncthreads();
  float hacc = 0.f;
  for (int e = 0; e < cnt; ++e)
    hacc = fmaf(gv[w][e], b2f(X1b[(size_t)cs[w][e] * HG + lane]), hacc);
  const float h = fmaxf(hacc + b1[lane], 0.f);
  float x[16];
  #pragma unroll
  for (int cc = 0; cc < 16; ++cc) x[cc] = h * W2[lane * C + cc];
  #pragma unroll
  for (int s = 1; s < 64; s <<= 1)
    #pragma unroll
    for (int cc = 0; cc < 16; ++cc) x[cc] += __shfl_xor(x[cc], s);
  float v = x[0];
  #pragma unroll
  for (int cc = 1; cc < 16; ++cc) v = (lane == cc) ? x[cc] : v;
  if (lane < 16) X2[row * C + lane] = v;
}

// ---------------- K6: output = g @ X2 + b2 ; logits = softmax(output) --------------------------
__global__ __launch_bounds__(256) void gcn2(const float* __restrict__ X2,
    const float* __restrict__ b2, const int* __restrict__ rowcnt,
    const int* __restrict__ colidx, const float* __restrict__ gval,
    float* __restrict__ out_logits, float* __restrict__ out_output) {
  const int lane = threadIdx.x & 63;
  const int row = blockIdx.x * 4 + (threadIdx.x >> 6);
  const int c = lane & 15, grp = lane >> 4;
  const int cnt = rowcnt[row];
  float acc = 0.f;
  for (int e = grp; e < cnt; e += 4)
    acc = fmaf(gval[row * KMAX + e], X2[colidx[row * KMAX + e] * C + c], acc);
  acc += __shfl_xor(acc, 16);
  acc += __shfl_xor(acc, 32);
  acc += b2[c];
  float m = acc;
  for (int s = 1; s < 16; s <<= 1) m = fmaxf(m, __shfl_xor(m, s));
  const float e = __expf(acc - m);
  float ssum = e;
  for (int s = 1; s < 16; s <<= 1) ssum += __shfl_xor(ssum, s);
  if (lane < 16) {
    out_output[row * C + c] = acc;
    out_logits[row * C + c] = e / ssum;
  }
}

// ---------------- K7: losses (single block; launch boundary is the fence) ----------------------
__global__ __launch_bounds__(256) void loss_kernel(const float* __restrict__ logits,
    const float* __restrict__ Bmat, const int* __restrict__ idx,
    const int* __restrict__ label, float* __restrict__ out_loss) {
  __shared__ float sg[256], sm[256];
  const int t = threadIdx.x;
  float g = 0.f, m = 0.f;
  for (int i = t; i < 1024; i += 256) {
    const int ii = idx[i], ll = label[i];
    g -= logf(logits[ii * C + ll]);
    m -= logf(Bmat[ii * C + ll]);
  }
  sg[t] = g; sm[t] = m;
  __syncthreads();
  for (int s = 128; s > 0; s >>= 1) {
    if (t < s) { sg[t] += sg[t + s]; sm[t] += sm[t + s]; }
    __syncthreads();
  }
  if (t == 0) out_loss[0] = 1.0f * (sg[0] / 1024.f) + 1.0f * (sm[0] / 1024.f);
}

extern "C" void kernel_launch(void* const* d_in, const int* in_sizes, int n_in,
                              void* d_out, int out_size, void* d_ws, size_t ws_size,
                              hipStream_t stream) {
  const float* feature  = (const float*)d_in[0];
  const float* adj      = (const float*)d_in[1];
  const float* labels1h = (const float*)d_in[2];
  const float* bias     = (const float*)d_in[3];
  const float* Wm1 = (const float*)d_in[4];
  const float* bm1 = (const float*)d_in[5];
  const float* Wm2 = (const float*)d_in[6];
  const float* bm2 = (const float*)d_in[7];
  const float* W1  = (const float*)d_in[8];
  const float* b1  = (const float*)d_in[9];
  const float* W2  = (const float*)d_in[10];
  const float* b2  = (const float*)d_in[11];
  const int* idx   = (const int*)d_in[12];
  const int* label = (const int*)d_in[13];
  const int* mask  = (const int*)d_in[14];

  float* out = (float*)d_out;
  float* logits_o = out;                 // N*C
  float* loss_o   = out + (size_t)N * C; // 1
  float* H_o      = loss_o + 1;          // 256
  float* Q_o      = H_o + 256;           // 256
  float* outp_o   = Q_o + 256;           // N*C

  float* p = (float*)d_ws;
  float* Bmat   = p; p += (size_t)N * C;
  float* softy  = p; p += (size_t)N * C;
  float* nbrsum = p; p += (size_t)N * C;
  float* X2     = p; p += (size_t)N * C;
  float* Hpart  = p; p += 64 * 272;
  float* Qws    = p; p += 256;
  int* rowcnt = (int*)p; p += N;
  int* colidx = (int*)p; p += (size_t)N * KMAX;
  float* gval = p; p += (size_t)N * KMAX;
  unsigned short* X1b   = (unsigned short*)p; p += (size_t)N * HG / 2;  // bf16
  unsigned short* Wt    = (unsigned short*)p; p += 320 * 512 / 2;
  unsigned short* Wm2tb = (unsigned short*)p; p += 16 * 256 / 2;
  ull* bm = (ull*)p;                              // N*128 u64 = 8 MB

  tile_ballot<<<dim3(129, 65), 256, 0, stream>>>(adj, bm, Wm1, W1, Wm2, Wt, Wm2tb);
  gemm_mlp<<<N / 32, 256, 0, stream>>>(feature, (const bf16x8*)Wt, bm1,
      (const bf16x8*)Wm2tb, bm2, labels1h, mask, Bmat, softy, X1b);
  extract_nbr<<<N / 4, 256, 0, stream>>>(bm, rowcnt, colidx, softy, nbrsum);
  h_partial<<<64, 256, 0, stream>>>(nbrsum, softy, Hpart);
  hq_final<<<1, 256, 0, stream>>>(Hpart, bias, H_o, Q_o, Qws);
  edge_gcn1<<<N / 4, 256, 0, stream>>>(Bmat, Qws, rowcnt, colidx, X1b, b1, W2, gval, X2);
  gcn2<<<N / 4, 256, 0, stream>>>(X2, b2, rowcnt, colidx, gval, logits_o, outp_o);
  loss_kernel<<<1, 256, 0, stream>>>(logits_o, Bmat, idx, label, loss_o);
}

// Round 16
// 122.055 us; speedup vs baseline: 2.1764x; 1.0401x over previous
//
#include <hip/hip_runtime.h>
#include <math.h>

#define N   8192
#define D   512
#define C   16
#define HM  256
#define HG  64
#define KMAX 128   // max neighbors per row (mean ~65, 12-sigma safe)

typedef __attribute__((ext_vector_type(8))) short bf16x8;
typedef __attribute__((ext_vector_type(4))) float f32x4;
typedef unsigned long long ull;

__device__ __forceinline__ unsigned short f2b(float x) {
  union { float f; unsigned int u; } v; v.f = x;
  unsigned int r = v.u + 0x7FFFu + ((v.u >> 16) & 1u);  // RNE
  return (unsigned short)(r >> 16);
}
__device__ __forceinline__ float b2f(unsigned short b) {
  union { unsigned int u; float f; } v; v.u = ((unsigned int)b) << 16;
  return v.f;
}

// ---------------- K0: weight prep (tiny; must precede fused kernel) ----------------------------
__global__ __launch_bounds__(256) void wprep(const float* __restrict__ Wm1,
    const float* __restrict__ W1, const float* __restrict__ Wm2,
    unsigned short* __restrict__ Wt, unsigned short* __restrict__ Wm2tb) {
  const int tid = blockIdx.x * 256 + threadIdx.x;   // 640 blocks = 163840 threads
  {
    const int n = tid >> 9, k = tid & 511;
    Wt[tid] = f2b((n < 256) ? Wm1[k * 256 + n] : W1[k * 64 + (n - 256)]);
  }
  if (tid < 16 * 256) {
    const int cc = tid >> 8, k = tid & 255;
    Wm2tb[tid] = f2b(Wm2[k * 16 + cc]);
  }
}

// ---------------- K1: FUSED ballot (BW-bound, blocks 256..8511) + GEMM+MLP (blocks 0..255) -----
// 1-D grid 8512. Gemm blocks first => one per CU, runs under ballot's memory stream.
__global__ __launch_bounds__(256) void ballot_gemm(const float* __restrict__ adj,
    ull* __restrict__ bm, const float* __restrict__ feature,
    const bf16x8* __restrict__ Wt, const float* __restrict__ bm1,
    const bf16x8* __restrict__ Wm2tb, const float* __restrict__ bm2,
    const float* __restrict__ labels1h, const int* __restrict__ mask,
    float* __restrict__ Bmat, float* __restrict__ softy,
    unsigned short* __restrict__ X1b) {
  __shared__ __align__(16) char smem[32 * 264 * 2];   // union: c1[32][264] shorts | tb[64][68] bytes
  const int t = threadIdx.x;
  if (blockIdx.x >= 256) {
    // ---- ballot path: exact triangle via rectangle decode ----
    const int tri = blockIdx.x - 256;       // [0, 8256)
    const int p = tri / 129, q = tri % 129; // 64 x 129 rectangle
    int I, J;
    if (q < 128 - p) { I = p; J = p + q; }
    else             { I = 127 - p; J = q - 1; }
    unsigned char (*tb)[68] = (unsigned char(*)[68])smem;
    #pragma unroll
    for (int rr = 0; rr < 4; ++rr) {
      const int r = rr * 16 + (t >> 4);
      const int c = (t & 15) * 4;
      const float4 v = *(const float4*)&adj[(size_t)(I * 64 + r) * N + J * 64 + c];
      tb[r][c + 0] = v.x > 0.f;
      tb[r][c + 1] = v.y > 0.f;
      tb[r][c + 2] = v.z > 0.f;
      tb[r][c + 3] = v.w > 0.f;
    }
    __syncthreads();
    const int lane = t & 63, w = t >> 6;
    #pragma unroll
    for (int i = 0; i < 16; ++i) {
      const int r = w * 16 + i;
      const ull rw = __ballot(tb[r][lane] != 0);      // row word -> bm[I*64+r][J]
      if (lane == 0) bm[(size_t)(I * 64 + r) * 128 + J] = rw;
      const ull cw = __ballot(tb[lane][r] != 0);      // col word -> bm[J*64+r][I] (symmetry)
      if (lane == 0) bm[(size_t)(J * 64 + r) * 128 + I] = cw;
    }
    return;
  }
  // ---- GEMM path (blocks 0..255, BM=32, A converted on the fly) ----
  unsigned short (*c1)[264] = (unsigned short(*)[264])smem;
  const int l = t & 63, w = t >> 6;
  const int m0 = blockIdx.x * 32;
  const int kb = l >> 4, cl = l & 15;
  const int rw = (w >> 1) * 16;          // row half: 0 or 16
  const int nt0 = (w & 1) * 10;          // tile half: 0..9 or 10..19
  const int row = m0 + rw + cl;
  const float* arow = feature + (size_t)row * D + kb * 8;
  f32x4 acc[10] = {};
  for (int kk = 0; kk < 16; ++kk) {
    const float4 a0 = *(const float4*)&arow[kk * 32];
    const float4 a1 = *(const float4*)&arow[kk * 32 + 4];
    bf16x8 af;
    af[0] = f2b(a0.x); af[1] = f2b(a0.y); af[2] = f2b(a0.z); af[3] = f2b(a0.w);
    af[4] = f2b(a1.x); af[5] = f2b(a1.y); af[6] = f2b(a1.z); af[7] = f2b(a1.w);
    #pragma unroll
    for (int i = 0; i < 10; ++i) {
      const bf16x8 bfr = Wt[(size_t)((nt0 + i) * 16 + cl) * 64 + kk * 4 + kb];
      acc[i] = __builtin_amdgcn_mfma_f32_16x16x32_bf16(af, bfr, acc[i], 0, 0, 0);
    }
  }
  const int rl0 = rw + kb * 4;   // C/D layout: col=l&15, row=(l>>4)*4+r
  #pragma unroll
  for (int i = 0; i < 10; ++i) {
    const int nt = nt0 + i;
    const int col = nt * 16 + cl;
    if (nt < 16) {
      const float bv = bm1[col];
      #pragma unroll
      for (int r = 0; r < 4; ++r)
        c1[rl0 + r][col] = f2b(fmaxf(acc[i][r] + bv, 0.f));
    } else {
      const int xc = col - 256;
      #pragma unroll
      for (int r = 0; r < 4; ++r)
        X1b[(size_t)(m0 + rl0 + r) * HG + xc] = f2b(acc[i][r]);
    }
  }
  __syncthreads();
  if ((w & 1) == 0) {   // layer 2 (waves 0,2): B = softmax(C1 @ Wm2 + bm2)
    f32x4 acc2 = {0.f, 0.f, 0.f, 0.f};
    #pragma unroll
    for (int kk = 0; kk < 8; ++kk) {
      const bf16x8 a2 = *(const bf16x8*)&c1[rw + cl][kk * 32 + kb * 8];
      const bf16x8 b2v = Wm2tb[(size_t)cl * 32 + kk * 4 + kb];
      acc2 = __builtin_amdgcn_mfma_f32_16x16x32_bf16(a2, b2v, acc2, 0, 0, 0);
    }
    const float bm2v = bm2[cl];
    #pragma unroll
    for (int r = 0; r < 4; ++r) {
      float v = acc2[r] + bm2v;
      float m = v;
      #pragma unroll
      for (int s = 1; s < 16; s <<= 1) m = fmaxf(m, __shfl_xor(m, s));
      const float e = __expf(v - m);
      float ssum = e;
      #pragma unroll
      for (int s = 1; s < 16; s <<= 1) ssum += __shfl_xor(ssum, s);
      const float bb = e / ssum;
      const int grow = m0 + rw + kb * 4 + r;
      Bmat[grow * C + cl] = bb;
      softy[grow * C + cl] = mask[grow] ? labels1h[grow * C + cl] : bb;
    }
  }
}

// ---------------- K3: bitmask -> sorted ELL (no atomics, deterministic) + nbrsum ---------------
__global__ __launch_bounds__(256) void extract_nbr(const ull* __restrict__ bm,
    int* __restrict__ rowcnt, int* __restrict__ colidx,
    const float* __restrict__ softy, float* __restrict__ nbrsum) {
  __shared__ int cs[4][128];
  const int t = threadIdx.x, lane = t & 63, w = t >> 6;
  const int row = blockIdx.x * 4 + w;
  const ull w0 = bm[(size_t)row * 128 + lane];        // words 0..63
  const ull w1 = bm[(size_t)row * 128 + 64 + lane];   // words 64..127
  const int c0 = __builtin_popcountll(w0);
  const int c1 = __builtin_popcountll(w1);
  int s0 = c0, s1 = c1;
  #pragma unroll
  for (int s = 1; s < 64; s <<= 1) {
    const int y0 = __shfl_up(s0, s);
    const int y1 = __shfl_up(s1, s);
    if (lane >= s) { s0 += y0; s1 += y1; }
  }
  const int total0 = __shfl(s0, 63);
  const int total = total0 + __shfl(s1, 63);
  int off = s0 - c0;
  ull x = w0;
  while (x) {
    const int b = __builtin_ctzll(x);
    if (off < KMAX) {
      const int col = lane * 64 + b;
      colidx[(size_t)row * KMAX + off] = col;
      cs[w][off] = col;
    }
    ++off;
    x &= x - 1;
  }
  off = total0 + s1 - c1;
  x = w1;
  while (x) {
    const int b = __builtin_ctzll(x);
    if (off < KMAX) {
      const int col = (64 + lane) * 64 + b;
      colidx[(size_t)row * KMAX + off] = col;
      cs[w][off] = col;
    }
    ++off;
    x &= x - 1;
  }
  const int cnt = min(total, KMAX);
  if (lane == 0) rowcnt[row] = cnt;
  __syncthreads();
  const int cc = lane & 15, grp = lane >> 4;
  float acc = 0.f;
  for (int e = grp; e < cnt; e += 4)
    acc += softy[cs[w][e] * C + cc];
  acc += __shfl_xor(acc, 16);
  acc += __shfl_xor(acc, 32);
  if (lane < 16) nbrsum[row * C + cc] = acc;
}

// ---------------- K4a: partial H[c,c'] and d[c] over row slices (64 blocks) --------------------
__global__ __launch_bounds__(256) void h_partial(const float* __restrict__ nbrsum,
    const float* __restrict__ softy, float* __restrict__ Hpart) {
  const int t = threadIdx.x;
  const int c = t >> 4, cp = t & 15;
  float acc = 0.f, dacc = 0.f;
  const int j0 = blockIdx.x * (N / 64);
  for (int j = j0; j < j0 + N / 64; ++j) {
    const float nv = nbrsum[j * C + c];
    acc = fmaf(nv, softy[j * C + cp], acc);
    if (cp == 0) dacc += nv;
  }
  Hpart[blockIdx.x * 272 + t] = acc;
  if (cp == 0) Hpart[blockIdx.x * 272 + 256 + c] = dacc;
}

// ---------------- K4b: H = Hun/d ; Q = rownorm((H H^T)*bias)  (64 partials) --------------------
__global__ __launch_bounds__(256) void hq_final(const float* __restrict__ Hpart,
    const float* __restrict__ bias, float* __restrict__ H_out,
    float* __restrict__ Q_out, float* __restrict__ Qws) {
  __shared__ float Hs[256], Qs[256], rs[16], dd[16];
  const int t = threadIdx.x;
  const int c = t >> 4, cp = t & 15;
  float acc = 0.f;
  for (int b = 0; b < 64; ++b) acc += Hpart[b * 272 + t];
  if (t < 16) {
    float s = 0.f;
    for (int b = 0; b < 64; ++b) s += Hpart[b * 272 + 256 + t];
    dd[t] = s;
  }
  __syncthreads();
  const float Hv = acc / dd[c];
  Hs[t] = Hv;
  H_out[t] = Hv;
  __syncthreads();
  float q = 0.f;
  for (int k = 0; k < 16; ++k) q = fmaf(Hs[c * 16 + k], Hs[cp * 16 + k], q);
  q *= bias[t];
  Qs[t] = q;
  __syncthreads();
  if (t < 16) {
    float s = 0.f;
    for (int k = 0; k < 16; ++k) s += Qs[t * 16 + k];
    rs[t] = s;
  }
  __syncthreads();
  const float Qv = q / rs[c];
  Q_out[t] = Qv;
  Qws[t] = Qv;
}

// ---------------- K5: fused edge softmax + GCN layer1 (X1 bf16 gather) + X2 head ---------------
__global__ __launch_bounds__(256) void edge_gcn1(const float* __restrict__ Bmat,
    const float* __restrict__ Q, const int* __restrict__ rowcnt,
    const int* __restrict__ colidx, const unsigned short* __restrict__ X1b,
    const float* __restrict__ b1, const float* __restrict__ W2,
    float* __restrict__ gval, float* __restrict__ X2) {
  __shared__ float Prow[4][16];
  __shared__ float gv[4][128];
  __shared__ int cs[4][128];
  const int lane = threadIdx.x & 63, w = threadIdx.x >> 6;
  const int row = blockIdx.x * 4 + w;
  const int c = lane & 15, grp = lane >> 4;
  float acc = 0.f;
  for (int k = grp * 4; k < grp * 4 + 4; ++k)
    acc = fmaf(Bmat[row * C + k], Q[k * C + c], acc);
  acc += __shfl_xor(acc, 16);
  acc += __shfl_xor(acc, 32);
  if (lane < 16) Prow[w][c] = acc;
  __syncthreads();
  const int cnt = rowcnt[row];
  const int col0 = (lane < cnt) ? colidx[row * KMAX + lane] : 0;
  const int col1 = (lane + 64 < cnt) ? colidx[row * KMAX + lane + 64] : 0;
  float s0 = -1e30f, s1 = -1e30f;
  if (lane < cnt) {
    float s = 0.f;
    for (int k = 0; k < 16; ++k) s = fmaf(Prow[w][k], Bmat[col0 * C + k], s);
    s0 = s;
  }
  if (lane + 64 < cnt) {
    float s = 0.f;
    for (int k = 0; k < 16; ++k) s = fmaf(Prow[w][k], Bmat[col1 * C + k], s);
    s1 = s;
  }
  float m = fmaxf(s0, s1);
  for (int s = 1; s < 64; s <<= 1) m = fmaxf(m, __shfl_xor(m, s));
  const float e0 = __expf(s0 - m), e1 = __expf(s1 - m);
  float ssum = e0 + e1;
  for (int s = 1; s < 64; s <<= 1) ssum += __shfl_xor(ssum, s);
  const float inv = 1.f / ssum;
  const float g0 = e0 * inv, g1 = e1 * inv;
  if (lane < cnt) gval[row * KMAX + lane] = g0;
  if (lane + 64 < cnt) gval[row * KMAX + lane + 64] = g1;
  gv[w][lane] = g0; gv[w][lane + 64] = g1;
  cs[w][lane] = col0; cs[w][lane + 64] = col1;
  __syncthreads();
  float hacc = 0.f;
  for (int e = 0; e < cnt; ++e)
    hacc = fmaf(gv[w][e], b2f(X1b[(size_t)cs[w][e] * HG + lane]), hacc);
  const float h = fmaxf(hacc + b1[lane], 0.f);
  float x[16];
  #pragma unroll
  for (int cc = 0; cc < 16; ++cc) x[cc] = h * W2[lane * C + cc];
  #pragma unroll
  for (int s = 1; s < 64; s <<= 1)
    #pragma unroll
    for (int cc = 0; cc < 16; ++cc) x[cc] += __shfl_xor(x[cc], s);
  float v = x[0];
  #pragma unroll
  for (int cc = 1; cc < 16; ++cc) v = (lane == cc) ? x[cc] : v;
  if (lane < 16) X2[row * C + lane] = v;
}

// ---------------- K6: output = g @ X2 + b2 ; logits = softmax(output) --------------------------
__global__ __launch_bounds__(256) void gcn2(const float* __restrict__ X2,
    const float* __restrict__ b2, const int* __restrict__ rowcnt,
    const int* __restrict__ colidx, const float* __restrict__ gval,
    float* __restrict__ out_logits, float* __restrict__ out_output) {
  const int lane = threadIdx.x & 63;
  const int row = blockIdx.x * 4 + (threadIdx.x >> 6);
  const int c = lane & 15, grp = lane >> 4;
  const int cnt = rowcnt[row];
  float acc = 0.f;
  for (int e = grp; e < cnt; e += 4)
    acc = fmaf(gval[row * KMAX + e], X2[colidx[row * KMAX + e] * C + c], acc);
  acc += __shfl_xor(acc, 16);
  acc += __shfl_xor(acc, 32);
  acc += b2[c];
  float m = acc;
  for (int s = 1; s < 16; s <<= 1) m = fmaxf(m, __shfl_xor(m, s));
  const float e = __expf(acc - m);
  float ssum = e;
  for (int s = 1; s < 16; s <<= 1) ssum += __shfl_xor(ssum, s);
  if (lane < 16) {
    out_output[row * C + c] = acc;
    out_logits[row * C + c] = e / ssum;
  }
}

// ---------------- K7: losses (single block; launch boundary is the fence) ----------------------
__global__ __launch_bounds__(256) void loss_kernel(const float* __restrict__ logits,
    const float* __restrict__ Bmat, const int* __restrict__ idx,
    const int* __restrict__ label, float* __restrict__ out_loss) {
  __shared__ float sg[256], sm[256];
  const int t = threadIdx.x;
  float g = 0.f, m = 0.f;
  for (int i = t; i < 1024; i += 256) {
    const int ii = idx[i], ll = label[i];
    g -= logf(logits[ii * C + ll]);
    m -= logf(Bmat[ii * C + ll]);
  }
  sg[t] = g; sm[t] = m;
  __syncthreads();
  for (int s = 128; s > 0; s >>= 1) {
    if (t < s) { sg[t] += sg[t + s]; sm[t] += sm[t + s]; }
    __syncthreads();
  }
  if (t == 0) out_loss[0] = 1.0f * (sg[0] / 1024.f) + 1.0f * (sm[0] / 1024.f);
}

extern "C" void kernel_launch(void* const* d_in, const int* in_sizes, int n_in,
                              void* d_out, int out_size, void* d_ws, size_t ws_size,
                              hipStream_t stream) {
  const float* feature  = (const float*)d_in[0];
  const float* adj      = (const float*)d_in[1];
  const float* labels1h = (const float*)d_in[2];
  const float* bias     = (const float*)d_in[3];
  const float* Wm1 = (const float*)d_in[4];
  const float* bm1 = (const float*)d_in[5];
  const float* Wm2 = (const float*)d_in[6];
  const float* bm2 = (const float*)d_in[7];
  const float* W1  = (const float*)d_in[8];
  const float* b1  = (const float*)d_in[9];
  const float* W2  = (const float*)d_in[10];
  const float* b2  = (const float*)d_in[11];
  const int* idx   = (const int*)d_in[12];
  const int* label = (const int*)d_in[13];
  const int* mask  = (const int*)d_in[14];

  float* out = (float*)d_out;
  float* logits_o = out;                 // N*C
  float* loss_o   = out + (size_t)N * C; // 1
  float* H_o      = loss_o + 1;          // 256
  float* Q_o      = H_o + 256;           // 256
  float* outp_o   = Q_o + 256;           // N*C

  float* p = (float*)d_ws;
  float* Bmat   = p; p += (size_t)N * C;
  float* softy  = p; p += (size_t)N * C;
  float* nbrsum = p; p += (size_t)N * C;
  float* X2     = p; p += (size_t)N * C;
  float* Hpart  = p; p += 64 * 272;
  float* Qws    = p; p += 256;
  int* rowcnt = (int*)p; p += N;
  int* colidx = (int*)p; p += (size_t)N * KMAX;
  float* gval = p; p += (size_t)N * KMAX;
  unsigned short* X1b   = (unsigned short*)p; p += (size_t)N * HG / 2;  // bf16
  unsigned short* Wt    = (unsigned short*)p; p += 320 * 512 / 2;
  unsigned short* Wm2tb = (unsigned short*)p; p += 16 * 256 / 2;
  ull* bm = (ull*)p;                              // N*128 u64 = 8 MB

  wprep<<<640, 256, 0, stream>>>(Wm1, W1, Wm2, Wt, Wm2tb);
  ballot_gemm<<<256 + 8256, 256, 0, stream>>>(adj, bm, feature, (const bf16x8*)Wt,
      bm1, (const bf16x8*)Wm2tb, bm2, labels1h, mask, Bmat, softy, X1b);
  extract_nbr<<<N / 4, 256, 0, stream>>>(bm, rowcnt, colidx, softy, nbrsum);
  h_partial<<<64, 256, 0, stream>>>(nbrsum, softy, Hpart);
  hq_final<<<1, 256, 0, stream>>>(Hpart, bias, H_o, Q_o, Qws);
  edge_gcn1<<<N / 4, 256, 0, stream>>>(Bmat, Qws, rowcnt, colidx, X1b, b1, W2, gval, X2);
  gcn2<<<N / 4, 256, 0, stream>>>(X2, b2, rowcnt, colidx, gval, logits_o, outp_o);
  loss_kernel<<<1, 256, 0, stream>>>(logits_o, Bmat, idx, label, loss_o);
}